// Round 3
// baseline (566.195 us; speedup 1.0000x reference)
//
#include <hip/hip_runtime.h>
#include <math.h>

// Problem constants
#define NCOL 32768          // N = 32*32*32 columns
#define KAT  512            // dictionary atoms
#define DIM  64             // embedding dim

// Output flat offsets (fp32 elements)
#define O_LOSS  0
#define O_RECON 1
#define O_ZF    2097153     // 1 + 2097152
#define O_PERP  4194305
#define O_GAMMA 4194306

// Workspace layout (fp32 elements)
#define WS_DN   0           // Dn  [64][512]
#define WS_DNT  32768       // DnT [512][64]
#define WS_G    65536       // G   [512][512]
#define WS_ACC  327680      // acc[0]=sum((recon-zf)^2), acc[1]=sum_n S_n

// ---------------------------------------------------------------------------
// Kernel 1: normalize dictionary columns -> Dn, DnT; zero accumulators.
__global__ void prep_kernel(const float* __restrict__ dict, float* __restrict__ ws) {
    float* Dn  = ws + WS_DN;
    float* DnT = ws + WS_DNT;
    float* acc = ws + WS_ACC;
    int a = threadIdx.x;              // 512 threads, 1 block
    if (a < 2) acc[a] = 0.f;
    float s = 0.f;
    #pragma unroll
    for (int d = 0; d < DIM; ++d) { float v = dict[d*KAT + a]; s += v * v; }
    float nrm = sqrtf(s);
    #pragma unroll
    for (int d = 0; d < DIM; ++d) {
        float v = dict[d*KAT + a] / nrm;
        Dn[d*KAT + a]  = v;
        DnT[a*DIM + d] = v;
    }
}

// ---------------------------------------------------------------------------
// Kernel 2: G = Dn^T Dn.  block = row i (512 blocks), thread = col j (512).
__global__ void gram_kernel(const float* __restrict__ ws_in, float* __restrict__ ws) {
    const float* Dn = ws_in + WS_DN;
    float* G = ws + WS_G;
    int i = blockIdx.x, j = threadIdx.x;
    float s = 0.f;
    #pragma unroll
    for (int d = 0; d < DIM; ++d)
        s = fmaf(Dn[d*KAT + i], Dn[d*KAT + j], s);
    G[i*KAT + j] = s;
}

// ---------------------------------------------------------------------------
// Kernel 3: zf output = permutation gather of z_e, LDS-tiled for coalescing.
__global__ __launch_bounds__(256) void zf_kernel(const float* __restrict__ z_e,
                                                 float* __restrict__ out) {
    __shared__ float tile[64 * 33];   // [c][w], pad to 33 -> conflict-free
    int s = blockIdx.x;               // 1024 blocks: one (b,h) slab each
    int b = s >> 5, h = s & 31;
    int t = threadIdx.x;
    int srcbase = b * 65536 + h * 32;
    #pragma unroll
    for (int i = 0; i < 8; ++i) {
        int e = t + i * 256;          // e = c*32 + w
        int c = e >> 5, w = e & 31;
        tile[c * 33 + w] = z_e[srcbase + c * 1024 + w];
    }
    __syncthreads();
    int obase = O_ZF + s * 2048;
    #pragma unroll
    for (int i = 0; i < 8; ++i) {
        int e = t + i * 256;          // e = w*64 + c
        out[obase + e] = tile[(e & 63) * 33 + (e >> 6)];
    }
}

// ---------------------------------------------------------------------------
// Kernel 4: zero-fill gamma region (64 MiB). float2: region only 8B-aligned.
__global__ void gzero_kernel(float2* __restrict__ g2) {
    int id = blockIdx.x * 256 + threadIdx.x;   // 8192 blocks
    #pragma unroll
    for (int i = 0; i < 4; ++i)
        g2[id + i * 2097152] = make_float2(0.f, 0.f);
}

// ---------------------------------------------------------------------------
// Kernel 5: fused h_bar + Batch-OMP, shuffle-identity formulation.
// 8 columns per 256-thread block (2 per wave).  Identities used:
//   L[k][j] = u_j[idx_k]      (Cholesky row = previous u's at the new atom)
//   y_k     = h[idx_k]*invd[k] (signed argmax winner gives the fwd-solve term)
// so the per-iteration serial Cholesky/forward-solve collapses to k+1
// independent shuffles + one rsqrt; G-row prefetch overlaps shuffle latency.
__global__ __launch_bounds__(256, 4) void omp_kernel(const float* __restrict__ z_e,
                                                     const float* __restrict__ ws,
                                                     float* __restrict__ out,
                                                     float* __restrict__ wsw) {
    const float* Dn  = ws + WS_DN;
    const float* DnT = ws + WS_DNT;
    const float* G   = ws + WS_G;
    float* acc = wsw + WS_ACC;

    __shared__ float xcols[DIM * 8];      // [d][c]  2 KB  (for h_bar GEMM)
    __shared__ float xcolsT[8 * DIM];     // [c][d]  2 KB  (conflict-free xd read)
    __shared__ float hbar[8 * KAT];       // [c][a] 16 KB

    const int t = threadIdx.x;
    const int n_base = blockIdx.x * 8;

    // ---- Phase 1: gather data columns
    #pragma unroll
    for (int i = 0; i < 2; ++i) {
        int e = t + i * 256;              // 0..511
        int d = e >> 3, c = e & 7;
        int L = d * NCOL + n_base + c;
        int src = (L >> 16) * 65536 + (L & 63) * 1024 + (((L >> 11) & 31) << 5) + ((L >> 6) & 31);
        float v = z_e[src];
        xcols[e] = v;
        xcolsT[c * DIM + d] = v;
    }
    __syncthreads();

    // ---- Phase 2: h_bar tile (Dn read once per block)
    {
        float a0[8], a1[8];
        #pragma unroll
        for (int i = 0; i < 8; ++i) { a0[i] = 0.f; a1[i] = 0.f; }
        const float4* xc4 = (const float4*)xcols;
        for (int d = 0; d < DIM; ++d) {
            float v0 = Dn[d * KAT + t];
            float v1 = Dn[d * KAT + 256 + t];
            #pragma unroll
            for (int q = 0; q < 2; ++q) {
                float4 xv = xc4[d * 2 + q];
                a0[q*4+0] = fmaf(v0, xv.x, a0[q*4+0]);
                a0[q*4+1] = fmaf(v0, xv.y, a0[q*4+1]);
                a0[q*4+2] = fmaf(v0, xv.z, a0[q*4+2]);
                a0[q*4+3] = fmaf(v0, xv.w, a0[q*4+3]);
                a1[q*4+0] = fmaf(v1, xv.x, a1[q*4+0]);
                a1[q*4+1] = fmaf(v1, xv.y, a1[q*4+1]);
                a1[q*4+2] = fmaf(v1, xv.z, a1[q*4+2]);
                a1[q*4+3] = fmaf(v1, xv.w, a1[q*4+3]);
            }
        }
        #pragma unroll
        for (int c = 0; c < 8; ++c) {
            hbar[c * KAT + t]       = a0[c];
            hbar[c * KAT + 256 + t] = a1[c];
        }
    }
    __syncthreads();

    // ---- Phase 3: OMP, one wave per column, 2 columns sequentially
    const int wv = t >> 6, lane = t & 63;
    float wv_sq = 0.f, wv_S = 0.f;

    #pragma unroll 1
    for (int cc = 0; cc < 2; ++cc) {
        const int col = wv * 2 + cc;
        const int n = n_base + col;
        const float* hbcol = hbar + col * KAT;

        float h[8];
        #pragma unroll
        for (int r = 0; r < 8; ++r) h[r] = hbcol[(r << 6) + lane];

        unsigned msk = 0;
        float uv[56];                 // u_0..u_6, uv[j*8+r]
        float Lr[28];                 // off-diag rows 1..7: Lr[i*(i-1)/2+j], j<i
        float invd[8], yv[8], xr[8];
        int Iv[8];

        #pragma unroll
        for (int k = 0; k < 8; ++k) {
            // argmax |h| over unmasked; exact first-index tie-break via u64 key
            float bv = -1.f; int bi = 0;
            #pragma unroll
            for (int r = 0; r < 8; ++r) {
                float av = ((msk >> r) & 1) ? -1.f : fabsf(h[r]);
                if (av > bv) { bv = av; bi = (r << 6) | lane; }
            }
            unsigned long long key = (bv >= 0.f)
                ? ((((unsigned long long)__float_as_uint(bv)) << 32) | (unsigned)(511 - bi))
                : 0ull;
            #pragma unroll
            for (int off = 32; off; off >>= 1) {
                unsigned long long ok = __shfl_xor(key, off, 64);
                if (ok > key) key = ok;
            }
            const int idx = 511 - (int)(key & 511u);    // wave-uniform
            const int rwin = idx >> 6, lwin = idx & 63;
            if (lwin == lane) msk |= 1u << rwin;
            Iv[k] = idx;

            // prefetch new G row immediately (overlaps shuffle latency below)
            const float* grow = G + idx * KAT;
            float gk[8];
            if (k < 7) {
                #pragma unroll
                for (int r = 0; r < 8; ++r) gk[r] = grow[(r << 6) + lane];
            }

            // signed winner h[idx] via uniform select + one shuffle
            float hsel = h[0];
            #pragma unroll
            for (int r = 1; r < 8; ++r) if (rwin == r) hsel = h[r];
            float hwin = __shfl(hsel, lwin, 64);

            // Cholesky row L[k][j] = u_j[idx] via k independent shuffles
            float Lk[7];
            #pragma unroll
            for (int j = 0; j < 7; ++j) if (j < k) {
                float us = uv[j*8 + 0];
                #pragma unroll
                for (int r = 1; r < 8; ++r) if (rwin == r) us = uv[j*8 + r];
                Lk[j] = __shfl(us, lwin, 64);
            }
            float s2 = 0.f;
            #pragma unroll
            for (int j = 0; j < 7; ++j) if (j < k) {
                Lr[k*(k-1)/2 + j] = Lk[j];
                s2 += Lk[j] * Lk[j];
            }
            invd[k] = (k == 0) ? 1.f : 1.f / sqrtf(1.f - s2);
            yv[k] = hwin * invd[k];

            // u_k and incremental h update (not needed after last pick)
            if (k < 7) {
                #pragma unroll
                for (int r = 0; r < 8; ++r) {
                    float a = gk[r];
                    #pragma unroll
                    for (int j = 0; j < 7; ++j) if (j < k) a = fmaf(-Lk[j], uv[j*8 + r], a);
                    a *= invd[k];
                    uv[k*8 + r] = a;
                    h[r] = fmaf(-yv[k], a, h[r]);
                }
            }
        }

        // single back solve: L^T xr = yv
        #pragma unroll
        for (int i = 7; i >= 0; --i) {
            float a = yv[i];
            #pragma unroll
            for (int j = 0; j < 8; ++j) if (j > i) a = fmaf(-Lr[j*(j-1)/2 + i], xr[j], a);
            xr[i] = a * invd[i];
        }

        // ---- outputs for this column ----
        #pragma unroll
        for (int j = 0; j < 8; ++j)
            if (lane == j) out[O_GAMMA + Iv[j] * NCOL + n] = xr[j];

        // recon (lane = d), through the output permutation
        float rec = 0.f;
        #pragma unroll
        for (int j = 0; j < 8; ++j)
            rec = fmaf(xr[j], DnT[Iv[j] * DIM + lane], rec);
        int L = lane * NCOL + n;
        int perm = (L >> 16) * 65536 + (L & 63) * 1024 + (((L >> 11) & 31) << 5) + ((L >> 6) & 31);
        out[O_RECON + perm] = rec;

        // squared-error partial (conflict-free read)
        float xd = xcolsT[col * DIM + lane];
        float diff = rec - xd;
        float sq = diff * diff;
        #pragma unroll
        for (int off = 32; off; off >>= 1) sq += __shfl_xor(sq, off, 64);
        if (lane == 0) wv_sq += sq;

        // softmax-entropy term: 8 nnz + 504 zeros
        if (lane == 0) {
            float m = 0.f;
            #pragma unroll
            for (int j = 0; j < 8; ++j) m = fmaxf(m, xr[j]);
            float e0 = expf(-m);
            float Z = 504.f * e0;
            float es[8];
            #pragma unroll
            for (int j = 0; j < 8; ++j) { es[j] = expf(xr[j] - m); Z += es[j]; }
            float invZ = 1.f / Z;
            float p0 = e0 * invZ;
            float S = 504.f * p0 * logf(p0 + 1e-10f);
            #pragma unroll
            for (int j = 0; j < 8; ++j) { float p = es[j] * invZ; S += p * logf(p + 1e-10f); }
            wv_S += S;
        }
    }

    if (lane == 0) {
        atomicAdd(&acc[0], wv_sq);
        atomicAdd(&acc[1], wv_S);
    }
}

// ---------------------------------------------------------------------------
// Kernel 6: finalize scalars.
__global__ void fin_kernel(const float* __restrict__ ws, const float* __restrict__ beta,
                           float* __restrict__ out) {
    const float* acc = ws + WS_ACC;
    float mse = acc[0] / 2097152.f;                 // mean over 64*32768
    out[O_LOSS] = mse * 0.25f + beta[0] * mse;      // e_latent*cost + beta*q
    out[O_PERP] = expf(-acc[1] / 32768.f);
}

// ---------------------------------------------------------------------------
extern "C" void kernel_launch(void* const* d_in, const int* in_sizes, int n_in,
                              void* d_out, int out_size, void* d_ws, size_t ws_size,
                              hipStream_t stream) {
    const float* z_e  = (const float*)d_in[0];
    const float* dict = (const float*)d_in[1];
    const float* beta = (const float*)d_in[2];
    float* out = (float*)d_out;
    float* ws  = (float*)d_ws;

    prep_kernel<<<1, 512, 0, stream>>>(dict, ws);
    gram_kernel<<<512, 512, 0, stream>>>(ws, ws);
    zf_kernel<<<1024, 256, 0, stream>>>(z_e, out);
    gzero_kernel<<<8192, 256, 0, stream>>>((float2*)(out + O_GAMMA));
    omp_kernel<<<4096, 256, 0, stream>>>(z_e, ws, out, ws);
    fin_kernel<<<1, 1, 0, stream>>>(ws, beta, out);
}

// Round 4
// 561.668 us; speedup vs baseline: 1.0081x; 1.0081x over previous
//
#include <hip/hip_runtime.h>
#include <math.h>

// Problem constants
#define NCOL 32768          // N = 32*32*32 columns
#define KAT  512            // dictionary atoms
#define DIM  64             // embedding dim

// Output flat offsets (fp32 elements)
#define O_LOSS  0
#define O_RECON 1
#define O_ZF    2097153     // 1 + 2097152
#define O_PERP  4194305
#define O_GAMMA 4194306

// Workspace layout (fp32 elements)
#define WS_DN   0           // Dn  [64][512]
#define WS_DNT  32768       // DnT [512][64]
#define WS_G    65536       // G   [512][512]
#define WS_ACC  327680      // acc[0]=sum((recon-zf)^2), acc[1]=sum_n S_n

__device__ __forceinline__ float rlane(float v, int l) {
    return __uint_as_float(__builtin_amdgcn_readlane(__float_as_uint(v), l));
}

// ---------------------------------------------------------------------------
// Kernel 1: normalize dictionary columns -> Dn, DnT; zero accumulators.
__global__ void prep_kernel(const float* __restrict__ dict, float* __restrict__ ws) {
    float* Dn  = ws + WS_DN;
    float* DnT = ws + WS_DNT;
    float* acc = ws + WS_ACC;
    int a = threadIdx.x;              // 512 threads, 1 block
    if (a < 2) acc[a] = 0.f;
    float s = 0.f;
    #pragma unroll
    for (int d = 0; d < DIM; ++d) { float v = dict[d*KAT + a]; s += v * v; }
    float nrm = sqrtf(s);
    #pragma unroll
    for (int d = 0; d < DIM; ++d) {
        float v = dict[d*KAT + a] / nrm;
        Dn[d*KAT + a]  = v;
        DnT[a*DIM + d] = v;
    }
}

// ---------------------------------------------------------------------------
// Kernel 2: G = Dn^T Dn.  block = row i (512 blocks), thread = col j (512).
__global__ void gram_kernel(const float* __restrict__ ws_in, float* __restrict__ ws) {
    const float* Dn = ws_in + WS_DN;
    float* G = ws + WS_G;
    int i = blockIdx.x, j = threadIdx.x;
    float s = 0.f;
    #pragma unroll
    for (int d = 0; d < DIM; ++d)
        s = fmaf(Dn[d*KAT + i], Dn[d*KAT + j], s);
    G[i*KAT + j] = s;
}

// ---------------------------------------------------------------------------
// Kernel 3: zf output = permutation gather of z_e, LDS-tiled for coalescing.
__global__ __launch_bounds__(256) void zf_kernel(const float* __restrict__ z_e,
                                                 float* __restrict__ out) {
    __shared__ float tile[64 * 33];   // [c][w], pad to 33 -> conflict-free
    int s = blockIdx.x;               // 1024 blocks: one (b,h) slab each
    int b = s >> 5, h = s & 31;
    int t = threadIdx.x;
    int srcbase = b * 65536 + h * 32;
    #pragma unroll
    for (int i = 0; i < 8; ++i) {
        int e = t + i * 256;          // e = c*32 + w
        int c = e >> 5, w = e & 31;
        tile[c * 33 + w] = z_e[srcbase + c * 1024 + w];
    }
    __syncthreads();
    int obase = O_ZF + s * 2048;
    #pragma unroll
    for (int i = 0; i < 8; ++i) {
        int e = t + i * 256;          // e = w*64 + c
        out[obase + e] = tile[(e & 63) * 33 + (e >> 6)];
    }
}

// ---------------------------------------------------------------------------
// Kernel 4: zero-fill gamma region (64 MiB). float2: region only 8B-aligned.
__global__ void gzero_kernel(float2* __restrict__ g2) {
    int id = blockIdx.x * 256 + threadIdx.x;   // 8192 blocks
    #pragma unroll
    for (int i = 0; i < 4; ++i)
        g2[id + i * 2097152] = make_float2(0.f, 0.f);
}

// ---------------------------------------------------------------------------
// Kernel 5: fused h_bar + Batch-OMP, shuffle-identity formulation.
// 8 columns per 256-thread block (2 per wave).  Identities:
//   L[k][j] = u_j[idx_k]       (Cholesky row = previous u's at the new atom)
//   y_k     = h[idx_k]*invd[k] (signed argmax winner gives the fwd-solve term)
// idx is made wave-uniform via readfirstlane so slot selection is a scalar
// branch and broadcasts are v_readlane (L rows live in SGPRs -> low VGPR
// pressure, no launch-bounds cap, no scratch spills).
__global__ __launch_bounds__(256) void omp_kernel(const float* __restrict__ z_e,
                                                  const float* __restrict__ ws,
                                                  float* __restrict__ out,
                                                  float* __restrict__ wsw) {
    const float* Dn  = ws + WS_DN;
    const float* DnT = ws + WS_DNT;
    const float* G   = ws + WS_G;
    float* acc = wsw + WS_ACC;

    __shared__ float xcols[DIM * 8];      // [d][c]  2 KB  (for h_bar GEMM)
    __shared__ float xcolsT[8 * 65];      // [c][d]  pad 65 -> conflict-free
    __shared__ float hbar[8 * KAT];       // [c][a] 16 KB

    const int t = threadIdx.x;
    const int n_base = blockIdx.x * 8;

    // ---- Phase 1: gather data columns
    #pragma unroll
    for (int i = 0; i < 2; ++i) {
        int e = t + i * 256;              // 0..511
        int d = e >> 3, c = e & 7;
        int L = d * NCOL + n_base + c;
        int src = (L >> 16) * 65536 + (L & 63) * 1024 + (((L >> 11) & 31) << 5) + ((L >> 6) & 31);
        float v = z_e[src];
        xcols[e] = v;
        xcolsT[c * 65 + d] = v;
    }
    __syncthreads();

    // ---- Phase 2: h_bar tile (Dn read once per block)
    {
        float a0[8], a1[8];
        #pragma unroll
        for (int i = 0; i < 8; ++i) { a0[i] = 0.f; a1[i] = 0.f; }
        const float4* xc4 = (const float4*)xcols;
        for (int d = 0; d < DIM; ++d) {
            float v0 = Dn[d * KAT + t];
            float v1 = Dn[d * KAT + 256 + t];
            #pragma unroll
            for (int q = 0; q < 2; ++q) {
                float4 xv = xc4[d * 2 + q];
                a0[q*4+0] = fmaf(v0, xv.x, a0[q*4+0]);
                a0[q*4+1] = fmaf(v0, xv.y, a0[q*4+1]);
                a0[q*4+2] = fmaf(v0, xv.z, a0[q*4+2]);
                a0[q*4+3] = fmaf(v0, xv.w, a0[q*4+3]);
                a1[q*4+0] = fmaf(v1, xv.x, a1[q*4+0]);
                a1[q*4+1] = fmaf(v1, xv.y, a1[q*4+1]);
                a1[q*4+2] = fmaf(v1, xv.z, a1[q*4+2]);
                a1[q*4+3] = fmaf(v1, xv.w, a1[q*4+3]);
            }
        }
        #pragma unroll
        for (int c = 0; c < 8; ++c) {
            hbar[c * KAT + t]       = a0[c];
            hbar[c * KAT + 256 + t] = a1[c];
        }
    }
    __syncthreads();

    // ---- Phase 3: OMP, one wave per column, 2 columns sequentially
    const int wv = t >> 6, lane = t & 63;
    float wv_sq = 0.f, wv_S = 0.f;

    #pragma unroll 1
    for (int cc = 0; cc < 2; ++cc) {
        const int col = wv * 2 + cc;
        const int n = n_base + col;
        const float* hbcol = hbar + col * KAT;

        float h[8];
        #pragma unroll
        for (int r = 0; r < 8; ++r) h[r] = hbcol[(r << 6) + lane];

        unsigned msk = 0;
        float uv[56];                 // u_0..u_6, uv[j*8+r]
        float Lr[28];                 // SGPR-resident (readlane-sourced) rows
        float invd[8], yv[8], xr[8];
        int Iv[8];

        #pragma unroll
        for (int k = 0; k < 8; ++k) {
            // argmax |h| over unmasked; exact first-index tie-break via u64 key
            float bv = -1.f; int bi = 0;
            #pragma unroll
            for (int r = 0; r < 8; ++r) {
                float av = ((msk >> r) & 1) ? -1.f : fabsf(h[r]);
                if (av > bv) { bv = av; bi = (r << 6) | lane; }
            }
            unsigned long long key = (bv >= 0.f)
                ? ((((unsigned long long)__float_as_uint(bv)) << 32) | (unsigned)(511 - bi))
                : 0ull;
            #pragma unroll
            for (int off = 32; off; off >>= 1) {
                unsigned long long ok = __shfl_xor(key, off, 64);
                if (ok > key) key = ok;
            }
            const int idx = __builtin_amdgcn_readfirstlane(511 - (int)(key & 511u));
            const int rwin = idx >> 6, lwin = idx & 63;   // SGPRs
            if (lwin == lane) msk |= 1u << rwin;
            Iv[k] = idx;

            // prefetch new G row immediately (overlaps the readlanes below)
            const float* grow = G + idx * KAT;
            float gk[8];
            if (k < 7) {
                #pragma unroll
                for (int r = 0; r < 8; ++r) gk[r] = grow[(r << 6) + lane];
            }

            // uniform slot select (scalar branch on rwin), then readlane bcast
            float hsel = 0.f, usel[7];
            #pragma unroll
            for (int j = 0; j < 7; ++j) usel[j] = 0.f;
            #pragma unroll
            for (int r = 0; r < 8; ++r) if (rwin == r) {
                hsel = h[r];
                #pragma unroll
                for (int j = 0; j < 7; ++j) if (j < k) usel[j] = uv[j*8 + r];
            }
            float hwin = rlane(hsel, lwin);               // h[idx], SGPR
            float Lk[7];
            float s2 = 0.f;
            #pragma unroll
            for (int j = 0; j < 7; ++j) if (j < k) {
                Lk[j] = rlane(usel[j], lwin);             // L[k][j] = u_j[idx]
                Lr[k*(k-1)/2 + j] = Lk[j];
                s2 = fmaf(Lk[j], Lk[j], s2);
            }
            invd[k] = (k == 0) ? 1.f : 1.f / sqrtf(1.f - s2);
            yv[k] = hwin * invd[k];

            // u_k and incremental h update (not needed after last pick)
            if (k < 7) {
                #pragma unroll
                for (int r = 0; r < 8; ++r) {
                    float a = gk[r];
                    #pragma unroll
                    for (int j = 0; j < 7; ++j) if (j < k) a = fmaf(-Lk[j], uv[j*8 + r], a);
                    a *= invd[k];
                    uv[k*8 + r] = a;
                    h[r] = fmaf(-yv[k], a, h[r]);
                }
            }
        }

        // single back solve: L^T xr = yv
        #pragma unroll
        for (int i = 7; i >= 0; --i) {
            float a = yv[i];
            #pragma unroll
            for (int j = 0; j < 8; ++j) if (j > i) a = fmaf(-Lr[j*(j-1)/2 + i], xr[j], a);
            xr[i] = a * invd[i];
        }

        // ---- outputs for this column ----
        #pragma unroll
        for (int j = 0; j < 8; ++j)
            if (lane == j) out[O_GAMMA + Iv[j] * NCOL + n] = xr[j];

        // recon (lane = d), through the output permutation
        float rec = 0.f;
        #pragma unroll
        for (int j = 0; j < 8; ++j)
            rec = fmaf(xr[j], DnT[Iv[j] * DIM + lane], rec);
        int L = lane * NCOL + n;
        int perm = (L >> 16) * 65536 + (L & 63) * 1024 + (((L >> 11) & 31) << 5) + ((L >> 6) & 31);
        out[O_RECON + perm] = rec;

        // squared-error partial (conflict-free read)
        float xd = xcolsT[col * 65 + lane];
        float diff = rec - xd;
        float sq = diff * diff;
        #pragma unroll
        for (int off = 32; off; off >>= 1) sq += __shfl_xor(sq, off, 64);
        if (lane == 0) wv_sq += sq;

        // softmax-entropy: 8 nnz + 504 zeros, parallel over lanes 0..7
        {
            float m = 0.f;
            #pragma unroll
            for (int j = 0; j < 8; ++j) m = fmaxf(m, xr[j]);
            float xsel = 0.f;
            #pragma unroll
            for (int j = 0; j < 8; ++j) xsel = (lane == j) ? xr[j] : xsel;
            float e = (lane < 8) ? expf(xsel - m) : 0.f;
            float se = e;
            #pragma unroll
            for (int off = 1; off < 8; off <<= 1) se += __shfl_xor(se, off, 64);
            float e0 = expf(-m);
            float Z = fmaf(504.f, e0, se);       // valid on lanes 0..7
            float invZ = 1.f / Z;
            float p = e * invZ;
            float tq = (lane < 8) ? p * logf(p + 1e-10f) : 0.f;
            #pragma unroll
            for (int off = 1; off < 8; off <<= 1) tq += __shfl_xor(tq, off, 64);
            if (lane == 0) {
                float p0 = e0 * invZ;
                wv_S += tq + 504.f * p0 * logf(p0 + 1e-10f);
            }
        }
    }

    if (lane == 0) {
        atomicAdd(&acc[0], wv_sq);
        atomicAdd(&acc[1], wv_S);
    }
}

// ---------------------------------------------------------------------------
// Kernel 6: finalize scalars.
__global__ void fin_kernel(const float* __restrict__ ws, const float* __restrict__ beta,
                           float* __restrict__ out) {
    const float* acc = ws + WS_ACC;
    float mse = acc[0] / 2097152.f;                 // mean over 64*32768
    out[O_LOSS] = mse * 0.25f + beta[0] * mse;      // e_latent*cost + beta*q
    out[O_PERP] = expf(-acc[1] / 32768.f);
}

// ---------------------------------------------------------------------------
extern "C" void kernel_launch(void* const* d_in, const int* in_sizes, int n_in,
                              void* d_out, int out_size, void* d_ws, size_t ws_size,
                              hipStream_t stream) {
    const float* z_e  = (const float*)d_in[0];
    const float* dict = (const float*)d_in[1];
    const float* beta = (const float*)d_in[2];
    float* out = (float*)d_out;
    float* ws  = (float*)d_ws;

    prep_kernel<<<1, 512, 0, stream>>>(dict, ws);
    gram_kernel<<<512, 512, 0, stream>>>(ws, ws);
    zf_kernel<<<1024, 256, 0, stream>>>(z_e, out);
    gzero_kernel<<<8192, 256, 0, stream>>>((float2*)(out + O_GAMMA));
    omp_kernel<<<4096, 256, 0, stream>>>(z_e, ws, out, ws);
    fin_kernel<<<1, 1, 0, stream>>>(ws, beta, out);
}

// Round 5
// 372.285 us; speedup vs baseline: 1.5209x; 1.5087x over previous
//
#include <hip/hip_runtime.h>
#include <math.h>

// Problem constants
#define NCOL 32768          // N = 32*32*32 columns
#define KAT  512            // dictionary atoms
#define DIM  64             // embedding dim

// Output flat offsets (fp32 elements)
#define O_LOSS  0
#define O_RECON 1
#define O_ZF    2097153     // 1 + 2097152
#define O_PERP  4194305
#define O_GAMMA 4194306

// Workspace layout (fp32 elements)
#define WS_DN   0           // Dn  [64][512]
#define WS_DNT  32768       // DnT [512][64]
#define WS_G    65536       // G   [512][512]
#define WS_ACC  327680      // acc[0]=sum((recon-zf)^2), acc[1]=sum_n S_n

// ---------------------------------------------------------------------------
// DPP wave-64 reductions (all-VALU, ~4cyc/stage; result broadcast via readlane)
__device__ __forceinline__ float wave_max_bcast_f32(float v) {
    int x = __float_as_int(v);
    int t;
    t = __builtin_amdgcn_update_dpp(x, x, 0x111, 0xf, 0xf, false);  // row_shr:1
    x = __float_as_int(fmaxf(__int_as_float(x), __int_as_float(t)));
    t = __builtin_amdgcn_update_dpp(x, x, 0x112, 0xf, 0xf, false);  // row_shr:2
    x = __float_as_int(fmaxf(__int_as_float(x), __int_as_float(t)));
    t = __builtin_amdgcn_update_dpp(x, x, 0x114, 0xf, 0xf, false);  // row_shr:4
    x = __float_as_int(fmaxf(__int_as_float(x), __int_as_float(t)));
    t = __builtin_amdgcn_update_dpp(x, x, 0x118, 0xf, 0xf, false);  // row_shr:8
    x = __float_as_int(fmaxf(__int_as_float(x), __int_as_float(t)));
    t = __builtin_amdgcn_update_dpp(x, x, 0x142, 0xa, 0xf, false);  // row_bcast:15
    x = __float_as_int(fmaxf(__int_as_float(x), __int_as_float(t)));
    t = __builtin_amdgcn_update_dpp(x, x, 0x143, 0xc, 0xf, false);  // row_bcast:31
    x = __float_as_int(fmaxf(__int_as_float(x), __int_as_float(t)));
    return __int_as_float(__builtin_amdgcn_readlane(x, 63));
}

__device__ __forceinline__ unsigned wave_min_bcast_u32(unsigned v) {
    int x = (int)v;
    int t;
    t = __builtin_amdgcn_update_dpp(x, x, 0x111, 0xf, 0xf, false);
    x = (int)min((unsigned)x, (unsigned)t);
    t = __builtin_amdgcn_update_dpp(x, x, 0x112, 0xf, 0xf, false);
    x = (int)min((unsigned)x, (unsigned)t);
    t = __builtin_amdgcn_update_dpp(x, x, 0x114, 0xf, 0xf, false);
    x = (int)min((unsigned)x, (unsigned)t);
    t = __builtin_amdgcn_update_dpp(x, x, 0x118, 0xf, 0xf, false);
    x = (int)min((unsigned)x, (unsigned)t);
    t = __builtin_amdgcn_update_dpp(x, x, 0x142, 0xa, 0xf, false);
    x = (int)min((unsigned)x, (unsigned)t);
    t = __builtin_amdgcn_update_dpp(x, x, 0x143, 0xc, 0xf, false);
    x = (int)min((unsigned)x, (unsigned)t);
    return (unsigned)__builtin_amdgcn_readlane(x, 63);
}

// ---------------------------------------------------------------------------
// Kernel 1: normalize dictionary columns -> Dn, DnT; zero accumulators.
__global__ void prep_kernel(const float* __restrict__ dict, float* __restrict__ ws) {
    float* Dn  = ws + WS_DN;
    float* DnT = ws + WS_DNT;
    float* acc = ws + WS_ACC;
    int a = threadIdx.x;              // 512 threads, 1 block
    if (a < 2) acc[a] = 0.f;
    float s = 0.f;
    #pragma unroll
    for (int d = 0; d < DIM; ++d) { float v = dict[d*KAT + a]; s += v * v; }
    float nrm = sqrtf(s);
    #pragma unroll
    for (int d = 0; d < DIM; ++d) {
        float v = dict[d*KAT + a] / nrm;
        Dn[d*KAT + a]  = v;
        DnT[a*DIM + d] = v;
    }
}

// ---------------------------------------------------------------------------
// Kernel 2: G = Dn^T Dn.  block = row i (512 blocks), thread = col j (512).
__global__ void gram_kernel(const float* __restrict__ ws_in, float* __restrict__ ws) {
    const float* Dn = ws_in + WS_DN;
    float* G = ws + WS_G;
    int i = blockIdx.x, j = threadIdx.x;
    float s = 0.f;
    #pragma unroll
    for (int d = 0; d < DIM; ++d)
        s = fmaf(Dn[d*KAT + i], Dn[d*KAT + j], s);
    G[i*KAT + j] = s;
}

// ---------------------------------------------------------------------------
// Kernel 3: zf output = permutation gather of z_e, LDS-tiled for coalescing.
__global__ __launch_bounds__(256) void zf_kernel(const float* __restrict__ z_e,
                                                 float* __restrict__ out) {
    __shared__ float tile[64 * 33];   // [c][w], pad to 33 -> conflict-free
    int s = blockIdx.x;               // 1024 blocks: one (b,h) slab each
    int b = s >> 5, h = s & 31;
    int t = threadIdx.x;
    int srcbase = b * 65536 + h * 32;
    #pragma unroll
    for (int i = 0; i < 8; ++i) {
        int e = t + i * 256;          // e = c*32 + w
        int c = e >> 5, w = e & 31;
        tile[c * 33 + w] = z_e[srcbase + c * 1024 + w];
    }
    __syncthreads();
    int obase = O_ZF + s * 2048;
    #pragma unroll
    for (int i = 0; i < 8; ++i) {
        int e = t + i * 256;          // e = w*64 + c
        out[obase + e] = tile[(e & 63) * 33 + (e >> 6)];
    }
}

// ---------------------------------------------------------------------------
// Kernel 4: zero-fill gamma region (64 MiB). float2: region only 8B-aligned.
__global__ void gzero_kernel(float2* __restrict__ g2) {
    int id = blockIdx.x * 256 + threadIdx.x;   // 8192 blocks
    #pragma unroll
    for (int i = 0; i < 4; ++i)
        g2[id + i * 2097152] = make_float2(0.f, 0.f);
}

// ---------------------------------------------------------------------------
// Kernel 5: fused h_bar + Batch-OMP. 16 columns per 256-thread block; one wave
// per column, 4 columns/wave. Argmax via two DPP reductions (exact value +
// exact first-index tie-break); y_k = h[idx]*invd[k] with h[idx] = +-maxv
// recovered by a sign ballot (no LDS read, no y-recurrence). Cholesky row via
// replicated w-recurrence from uniform (scalar) G loads — short 4-cyc FMA
// chains instead of long cross-lane chains.
__global__ __launch_bounds__(256) void omp_kernel(const float* __restrict__ z_e,
                                                  const float* __restrict__ ws,
                                                  float* __restrict__ out,
                                                  float* __restrict__ wsw) {
    const float* Dn  = ws + WS_DN;
    const float* DnT = ws + WS_DNT;
    const float* G   = ws + WS_G;
    float* acc = wsw + WS_ACC;

    __shared__ float xcols[DIM * 16];     // [d][c]  4 KB
    __shared__ float hbar[16 * KAT];      // [c][a] 32 KB

    const int t = threadIdx.x;
    const int n_base = blockIdx.x * 16;

    // ---- Phase 1: gather data columns
    #pragma unroll
    for (int i = 0; i < 4; ++i) {
        int e = t + i * 256;              // 0..1023
        int d = e >> 4, c = e & 15;
        int L = d * NCOL + n_base + c;
        int src = (L >> 16) * 65536 + (L & 63) * 1024 + (((L >> 11) & 31) << 5) + ((L >> 6) & 31);
        xcols[e] = z_e[src];
    }
    __syncthreads();

    // ---- Phase 2: h_bar tile (Dn read once per block)
    {
        float a0[16], a1[16];
        #pragma unroll
        for (int i = 0; i < 16; ++i) { a0[i] = 0.f; a1[i] = 0.f; }
        const float4* xc4 = (const float4*)xcols;
        for (int d = 0; d < DIM; ++d) {
            float v0 = Dn[d * KAT + t];
            float v1 = Dn[d * KAT + 256 + t];
            #pragma unroll
            for (int q = 0; q < 4; ++q) {
                float4 xv = xc4[d * 4 + q];
                a0[q*4+0] = fmaf(v0, xv.x, a0[q*4+0]);
                a0[q*4+1] = fmaf(v0, xv.y, a0[q*4+1]);
                a0[q*4+2] = fmaf(v0, xv.z, a0[q*4+2]);
                a0[q*4+3] = fmaf(v0, xv.w, a0[q*4+3]);
                a1[q*4+0] = fmaf(v1, xv.x, a1[q*4+0]);
                a1[q*4+1] = fmaf(v1, xv.y, a1[q*4+1]);
                a1[q*4+2] = fmaf(v1, xv.z, a1[q*4+2]);
                a1[q*4+3] = fmaf(v1, xv.w, a1[q*4+3]);
            }
        }
        #pragma unroll
        for (int c = 0; c < 16; ++c) {
            hbar[c * KAT + t]       = a0[c];
            hbar[c * KAT + 256 + t] = a1[c];
        }
    }
    __syncthreads();

    // ---- Phase 3: OMP, one wave per column, 4 columns sequentially
    const int wv = t >> 6, lane = t & 63;
    float wv_sq = 0.f, wv_S = 0.f;

    #pragma unroll 1
    for (int cc = 0; cc < 4; ++cc) {
        const int col = wv * 4 + cc;
        const int n = n_base + col;
        const float* hbcol = hbar + col * KAT;

        float h[8];
        #pragma unroll
        for (int r = 0; r < 8; ++r) h[r] = hbcol[(r << 6) + lane];

        unsigned msk = 0;
        float uv[56];                 // u_0..u_6, uv[j*8+r]
        float Lr[28];                 // off-diag rows 1..7: Lr[i*(i-1)/2+j], j<i
        float invd[8], yv[8], xr[8];
        int Iv[8];

        #pragma unroll
        for (int k = 0; k < 8; ++k) {
            // local argmax over this lane's 8 slots (track signed winner)
            float bv = -1.f; int bi = 0; float hb = 0.f;
            #pragma unroll
            for (int r = 0; r < 8; ++r) {
                float av = ((msk >> r) & 1) ? -1.f : fabsf(h[r]);
                bool gt = av > bv;
                bv = gt ? av : bv;
                bi = gt ? ((r << 6) | lane) : bi;
                hb = gt ? h[r] : hb;
            }
            // wave max, then first-index among exact ties via u32 min
            float maxv = wave_max_bcast_f32(bv);
            unsigned cand = (bv == maxv) ? (unsigned)bi : 0xffffffffu;
            const int idx = (int)wave_min_bcast_u32(cand);   // SGPR-uniform
            // signed winner h[idx] = +-maxv via one ballot
            unsigned long long sm = __ballot((bv == maxv) && (bi == idx) && (hb < 0.f));
            float hwin = (sm != 0ull) ? -maxv : maxv;

            if ((idx & 63) == lane) msk |= 1u << (idx >> 6);
            Iv[k] = idx;

            const float* grow = G + idx * KAT;   // scalar base
            // prefetch new G row (coalesced; also warms L1/L2 for grow[Iv[i]])
            float gk[8];
            if (k < 7) {
                #pragma unroll
                for (int r = 0; r < 8; ++r) gk[r] = grow[(r << 6) + lane];
            }

            // replicated Cholesky rank-1 extension (uniform scalar loads)
            float Lk[7];
            if (k == 0) {
                invd[0] = 1.f;
            } else {
                float s2 = 0.f;
                #pragma unroll
                for (int i = 0; i < 7; ++i) if (i < k) {
                    float a = grow[Iv[i]];              // == G[Iv[i]][idx]
                    #pragma unroll
                    for (int j = 0; j < 7; ++j) if (j < i) a = fmaf(-Lr[i*(i-1)/2 + j], Lk[j], a);
                    Lk[i] = a * invd[i];
                    s2 = fmaf(Lk[i], Lk[i], s2);
                }
                #pragma unroll
                for (int j = 0; j < 7; ++j) if (j < k) Lr[k*(k-1)/2 + j] = Lk[j];
                invd[k] = 1.f / sqrtf(1.f - s2);
            }
            yv[k] = hwin * invd[k];

            // u_k and incremental h update (not needed after last pick)
            if (k < 7) {
                #pragma unroll
                for (int r = 0; r < 8; ++r) {
                    float a = gk[r];
                    #pragma unroll
                    for (int j = 0; j < 7; ++j) if (j < k) a = fmaf(-Lk[j], uv[j*8 + r], a);
                    a *= invd[k];
                    uv[k*8 + r] = a;
                    h[r] = fmaf(-yv[k], a, h[r]);
                }
            }
        }

        // single back solve: L^T xr = yv
        #pragma unroll
        for (int i = 7; i >= 0; --i) {
            float a = yv[i];
            #pragma unroll
            for (int j = 0; j < 8; ++j) if (j > i) a = fmaf(-Lr[j*(j-1)/2 + i], xr[j], a);
            xr[i] = a * invd[i];
        }

        // ---- outputs for this column ----
        #pragma unroll
        for (int j = 0; j < 8; ++j)
            if (lane == j) out[O_GAMMA + Iv[j] * NCOL + n] = xr[j];

        // recon (lane = d), through the output permutation
        float rec = 0.f;
        #pragma unroll
        for (int j = 0; j < 8; ++j)
            rec = fmaf(xr[j], DnT[Iv[j] * DIM + lane], rec);
        int L = lane * NCOL + n;
        int perm = (L >> 16) * 65536 + (L & 63) * 1024 + (((L >> 11) & 31) << 5) + ((L >> 6) & 31);
        out[O_RECON + perm] = rec;

        // squared-error partial
        float xd = xcols[lane * 16 + col];
        float diff = rec - xd;
        float sq = diff * diff;
        #pragma unroll
        for (int off = 32; off; off >>= 1) sq += __shfl_xor(sq, off, 64);
        if (lane == 0) wv_sq += sq;

        // softmax-entropy: 8 nnz + 504 zeros, parallel over lanes 0..7
        {
            float m = 0.f;
            #pragma unroll
            for (int j = 0; j < 8; ++j) m = fmaxf(m, xr[j]);
            float xsel = 0.f;
            #pragma unroll
            for (int j = 0; j < 8; ++j) xsel = (lane == j) ? xr[j] : xsel;
            float e = (lane < 8) ? expf(xsel - m) : 0.f;
            float se = e;
            #pragma unroll
            for (int off = 1; off < 8; off <<= 1) se += __shfl_xor(se, off, 64);
            float e0 = expf(-m);
            float Z = fmaf(504.f, e0, se);       // valid on lanes 0..7
            float invZ = 1.f / Z;
            float p = e * invZ;
            float tq = (lane < 8) ? p * logf(p + 1e-10f) : 0.f;
            #pragma unroll
            for (int off = 1; off < 8; off <<= 1) tq += __shfl_xor(tq, off, 64);
            if (lane == 0) {
                float p0 = e0 * invZ;
                wv_S += tq + 504.f * p0 * logf(p0 + 1e-10f);
            }
        }
    }

    if (lane == 0) {
        atomicAdd(&acc[0], wv_sq);
        atomicAdd(&acc[1], wv_S);
    }
}

// ---------------------------------------------------------------------------
// Kernel 6: finalize scalars.
__global__ void fin_kernel(const float* __restrict__ ws, const float* __restrict__ beta,
                           float* __restrict__ out) {
    const float* acc = ws + WS_ACC;
    float mse = acc[0] / 2097152.f;                 // mean over 64*32768
    out[O_LOSS] = mse * 0.25f + beta[0] * mse;      // e_latent*cost + beta*q
    out[O_PERP] = expf(-acc[1] / 32768.f);
}

// ---------------------------------------------------------------------------
extern "C" void kernel_launch(void* const* d_in, const int* in_sizes, int n_in,
                              void* d_out, int out_size, void* d_ws, size_t ws_size,
                              hipStream_t stream) {
    const float* z_e  = (const float*)d_in[0];
    const float* dict = (const float*)d_in[1];
    const float* beta = (const float*)d_in[2];
    float* out = (float*)d_out;
    float* ws  = (float*)d_ws;

    prep_kernel<<<1, 512, 0, stream>>>(dict, ws);
    gram_kernel<<<512, 512, 0, stream>>>(ws, ws);
    zf_kernel<<<1024, 256, 0, stream>>>(z_e, out);
    gzero_kernel<<<8192, 256, 0, stream>>>((float2*)(out + O_GAMMA));
    omp_kernel<<<2048, 256, 0, stream>>>(z_e, ws, out, ws);
    fin_kernel<<<1, 1, 0, stream>>>(ws, beta, out);
}